// Round 1
// 141.750 us; speedup vs baseline: 1.0820x; 1.0820x over previous
//
#include <hip/hip_runtime.h>

// BCH truncated series on 3D periodic velocity fields — x-marching version.
// out_i = L_i + R_i + 0.25 * sum_j [ dL_i^j * R_j - dR_i^j * L_j ]
// (central differences, circulant bounds, channels-first (B,D,X,Y,Z)).
//
// Structure: each block owns an 8y x 128z column at fixed b and marches 8
// consecutive x-planes. A 4-plane register window (A=x-1, B=x, C=x+1,
// D=x+2 prefetch) supplies x-derivatives from registers; the current plane
// is staged in LDS so y-derivatives come from LDS (halo rows from global
// for tile-boundary threads only); z-derivatives come from width-32
// shuffles within the z-line. Global loads: ~9 float4/point vs 30+12 for
// the gather formulation.

namespace {
constexpr int Xd = 128, Yd = 128, Zd = 128, Dd = 3;
constexpr int Sd  = Xd * Yd * Zd;   // channel stride
constexpr int YZd = Yd * Zd;        // x-plane stride
constexpr int XSEG = 8;             // x-planes marched per block
constexpr int YT   = 8;             // y rows per block
constexpr int ZC   = 32;            // float4 chunks per z-line

__device__ inline float4 f4sub(float4 a, float4 b) {
    return make_float4(a.x - b.x, a.y - b.y, a.z - b.z, a.w - b.w);
}
__device__ inline float4 f4add(float4 a, float4 b) {
    return make_float4(a.x + b.x, a.y + b.y, a.z + b.z, a.w + b.w);
}
__device__ inline float4 f4mul(float4 a, float4 b) {
    return make_float4(a.x * b.x, a.y * b.y, a.z * b.z, a.w * b.w);
}
__device__ inline float4 f4fma(float4 a, float4 b, float4 c) {
    return make_float4(fmaf(a.x, b.x, c.x), fmaf(a.y, b.y, c.y),
                       fmaf(a.z, b.z, c.z), fmaf(a.w, b.w, c.w));
}
// c - a*b
__device__ inline float4 f4fms(float4 a, float4 b, float4 c) {
    return make_float4(fmaf(-a.x, b.x, c.x), fmaf(-a.y, b.y, c.y),
                       fmaf(-a.z, b.z, c.z), fmaf(-a.w, b.w, c.w));
}
} // namespace

__global__ void __launch_bounds__(256, 2)
bch_march(const float* __restrict__ L, const float* __restrict__ R,
          float* __restrict__ O)
{
    __shared__ float4 sP[2 * Dd][YT][ZC];   // 24 KB: [0..2]=L ch, [3..5]=R ch

    const int t  = threadIdx.x;
    const int zc = t & 31;          // z chunk (float4) within line
    const int ly = t >> 5;          // local y row 0..7

    int bb = blockIdx.x;            // grid = 2 * 16 * 16 = 512
    const int xs = bb & 15; bb >>= 4;   // x segment
    const int yt = bb & 15; bb >>= 4;   // y tile
    const int b  = bb;

    const int y  = yt * YT + ly;
    const int z0 = zc * 4;
    const int x0 = xs * XSEG;

    const int fbase = b * (Dd * Sd) + y * Zd + z0;
    const float* pL = L + fbase;
    const float* pR = R + fbase;
    float*       pO = O + fbase;

    const int oym = (((y - 1) & 127) - y) * Zd;   // wrapped y-1 row offset
    const int oyp = (((y + 1) & 127) - y) * Zd;   // wrapped y+1 row offset
    const int zlm = (zc + 31) & 31;   // shfl source lane for z-1 (.w)
    const int zlp = (zc + 1) & 31;    // shfl source lane for z+4 (.x)

    float4 AL[3], AR[3], BL[3], BR[3], CL[3], CR[3], DL[3], DR[3];

    auto loadP = [&](float4 (&PL)[3], float4 (&PR)[3], int xp) {
        const int off = xp * YZd;
#pragma unroll
        for (int d = 0; d < 3; ++d) {
            PL[d] = *(const float4*)(pL + off + d * Sd);
            PR[d] = *(const float4*)(pR + off + d * Sd);
        }
    };

    loadP(AL, AR, (x0 + 127) & 127);   // x0 - 1 (wrapped)
    loadP(BL, BR, x0);
    loadP(CL, CR, (x0 + 1) & 127);

#pragma unroll
    for (int s = 0; s < XSEG; ++s) {
        const int x    = x0 + s;
        const int xoff = x * YZd;

        // Prefetch plane x+2 (becomes C after rotation) — a full iteration
        // of latency tolerance for the center loads.
        if (s < XSEG - 1) loadP(DL, DR, (x + 2) & 127);

        // Halo rows from global for tile-boundary threads.
        float4 HmL[3], HmR[3], HpL[3], HpR[3];
        if (ly == 0) {
#pragma unroll
            for (int d = 0; d < 3; ++d) {
                HmL[d] = *(const float4*)(pL + xoff + oym + d * Sd);
                HmR[d] = *(const float4*)(pR + xoff + oym + d * Sd);
            }
        }
        if (ly == YT - 1) {
#pragma unroll
            for (int d = 0; d < 3; ++d) {
                HpL[d] = *(const float4*)(pL + xoff + oyp + d * Sd);
                HpR[d] = *(const float4*)(pR + xoff + oyp + d * Sd);
            }
        }

        // Stage current plane centers in LDS.
#pragma unroll
        for (int d = 0; d < 3; ++d) {
            sP[d][ly][zc]     = BL[d];
            sP[3 + d][ly][zc] = BR[d];
        }
        __syncthreads();

        // y-neighbors: LDS for interior rows, global halo at tile edges.
        const int lym = (ly == 0) ? 0 : ly - 1;          // clamped (safe read)
        const int lyp = (ly == YT - 1) ? YT - 1 : ly + 1;
        float4 yLm[3], yRm[3], yLp[3], yRp[3];
#pragma unroll
        for (int d = 0; d < 3; ++d) {
            yLm[d] = sP[d][lym][zc];     if (ly == 0)      yLm[d] = HmL[d];
            yRm[d] = sP[3 + d][lym][zc]; if (ly == 0)      yRm[d] = HmR[d];
            yLp[d] = sP[d][lyp][zc];     if (ly == YT - 1) yLp[d] = HpL[d];
            yRp[d] = sP[3 + d][lyp][zc]; if (ly == YT - 1) yRp[d] = HpR[d];
        }

#pragma unroll
        for (int i = 0; i < 3; ++i) {
            // j = 0 (x): from register window
            float4 dl = f4sub(CL[i], AL[i]);
            float4 dr = f4sub(CR[i], AR[i]);
            float4 br = f4fms(dr, BL[0], f4mul(dl, BR[0]));

            // j = 1 (y): from LDS / halo
            dl = f4sub(yLp[i], yLm[i]);
            dr = f4sub(yRp[i], yRm[i]);
            br = f4fms(dr, BL[1], f4fma(dl, BR[1], br));

            // j = 2 (z): shift-in-register + width-32 shuffles (wrap in line)
            const float lzm = __shfl(BL[i].w, zlm, 32);
            const float lzp = __shfl(BL[i].x, zlp, 32);
            const float rzm = __shfl(BR[i].w, zlm, 32);
            const float rzp = __shfl(BR[i].x, zlp, 32);
            dl = make_float4(BL[i].y - lzm, BL[i].z - BL[i].x,
                             BL[i].w - BL[i].y, lzp - BL[i].z);
            dr = make_float4(BR[i].y - rzm, BR[i].z - BR[i].x,
                             BR[i].w - BR[i].y, rzp - BR[i].z);
            br = f4fms(dr, BL[2], f4fma(dl, BR[2], br));

            float4 out = f4add(BL[i], BR[i]);
            const float4 q = make_float4(0.25f, 0.25f, 0.25f, 0.25f);
            out = f4fma(q, br, out);
            *(float4*)(pO + xoff + i * Sd) = out;
        }
        __syncthreads();   // protect LDS before next iteration's writes

        if (s < XSEG - 1) {
#pragma unroll
            for (int d = 0; d < 3; ++d) {
                AL[d] = BL[d]; BL[d] = CL[d]; CL[d] = DL[d];
                AR[d] = BR[d]; BR[d] = CR[d]; CR[d] = DR[d];
            }
        }
    }
}

extern "C" void kernel_launch(void* const* d_in, const int* in_sizes, int n_in,
                              void* d_out, int out_size, void* d_ws, size_t ws_size,
                              hipStream_t stream)
{
    const float* L = (const float*)d_in[0];
    const float* R = (const float*)d_in[1];
    float*       O = (float*)d_out;

    const int nblocks = 2 * (Yd / YT) * (Xd / XSEG);   // 512
    bch_march<<<dim3(nblocks), dim3(256), 0, stream>>>(L, R, O);
}